// Round 8
// baseline (97.988 us; speedup 1.0000x reference)
//
#include <hip/hip_runtime.h>
#include <stdint.h>

// B=32, C=2048, S=512, DC=128, P=768, ROW=896 f32 per (b,c) output row.
// Flat layout: thread t writes output float4-chunk t (perfectly sequential
// writes — round-4 structure, which measured 5.8 TB/s effective vs round-7's
// phase-split 5.56). The 4x pret re-read that plagued round 4 is fixed by an
// XCD-aware block swizzle: each XCD gets a CONTIGUOUS logical block range, so
// the ~3.5 consecutive blocks sharing one pret row hit the same XCD's L2.
// Round-6 lesson: no nontemporal hints (they cost ~0.9 TB/s).

typedef float f32x4 __attribute__((ext_vector_type(4)));

#define TOTAL_CHUNKS 14680064u   // 32*2048*896/4
#define NBLOCKS      57344u      // TOTAL_CHUNKS/256, divisible by 8
#define CPX          (NBLOCKS / 8u)   // 7168 logical blocks per XCD

__global__ __launch_bounds__(256) void EmbeddingLayer_14516989460967_kernel(
    const int*   __restrict__ seq,      // [B*C] int32
    const int*   __restrict__ offsets,  // [B*S*2] int32 (start,end)
    const float* __restrict__ table,    // [VOCAB*128] f32
    const float* __restrict__ pret,     // [B*S*768] f32
    float4*      __restrict__ out)      // f32 out viewed as 16B chunks
{
    // XCD swizzle: physical blocks round-robin XCDs (p -> XCD p%8); remap so
    // XCD k owns the contiguous logical range [k*CPX, (k+1)*CPX).
    uint32_t lb   = (blockIdx.x & 7u) * CPX + (blockIdx.x >> 3);
    uint32_t gtid = lb * 256u + threadIdx.x;

    uint32_t e   = gtid * 4u;             // f32 element index
    uint32_t row = e / 896u;              // (b,c) flat row
    uint32_t col = e - row * 896u;        // 0..892, multiple of 4

    f32x4 v;
    if (col < 128u) {
        // char-embedding segment: gather 16B of table row
        int tok = seq[row];
        v = *(const f32x4*)(table + (size_t)tok * 128u + col);
    } else {
        // scattered pretrained segment: pret[b, c/4]
        uint32_t b = row >> 11;           // row / 2048
        uint32_t c = row & 2047u;
        uint32_t p = c >> 2;
        int2 se = *(const int2*)(offsets + (((b << 9) + p) << 1));
        if ((int)c >= se.x && (int)c < se.y) {
            v = *(const f32x4*)(pret + (size_t)((b << 9) + p) * 768u + (col - 128u));
        } else {
            v = (f32x4){0.f, 0.f, 0.f, 0.f};
        }
    }
    ((f32x4*)out)[gtid] = v;
}

extern "C" void kernel_launch(void* const* d_in, const int* in_sizes, int n_in,
                              void* d_out, int out_size, void* d_ws, size_t ws_size,
                              hipStream_t stream) {
    const int*   seq     = (const int*)  d_in[0];
    const int*   offsets = (const int*)  d_in[1];
    const float* table   = (const float*)d_in[2];
    const float* pret    = (const float*)d_in[3];

    EmbeddingLayer_14516989460967_kernel<<<NBLOCKS, 256, 0, stream>>>(
        seq, offsets, table, pret, (float4*)d_out);
}

// Round 9
// 80.743 us; speedup vs baseline: 1.2136x; 1.2136x over previous
//
#include <hip/hip_runtime.h>
#include <stdint.h>

// B=32, C=2048, S=512, DC=128, P=768, ROW=896 f32 per (b,c) output row.
// Each 256-thread block produces a complete, contiguous 28 KB output region:
// 8 rows (= 2 subwords), 1792 float4 chunks, 7 chunks/thread.
//  - writes: perfectly sequential per block, rows complete (no hole-filling)
//  - pret: 4 rows share one vector -> re-reads hit this CU's L1 (6 KB footprint)
//  - table: random 512 B rows, L3-resident (16 MB << 256 MB)
// Lessons: no nontemporal (round 6, -0.9 TB/s); no XCD swizzle (round 8, cross-
// block reuse windows don't align for streaming ops — keep reuse in-block).

typedef float f32x4 __attribute__((ext_vector_type(4)));

#define NBLOCKS 8192u   // 65536 rows / 8 rows per block

__global__ __launch_bounds__(256) void EmbeddingLayer_14516989460967_kernel(
    const int*   __restrict__ seq,      // [B*C] int32
    const int*   __restrict__ offsets,  // [B*S*2] int32 (start,end)
    const float* __restrict__ table,    // [VOCAB*128] f32
    const float* __restrict__ pret,     // [B*S*768] f32
    f32x4*       __restrict__ out)      // f32 out viewed as 16B chunks
{
    uint32_t row0   = blockIdx.x * 8u;      // first output row of this block
    uint32_t chunk0 = blockIdx.x * 1792u;   // first float4 chunk of this block

#pragma unroll
    for (uint32_t k = 0; k < 7u; ++k) {
        uint32_t l   = k * 256u + threadIdx.x;  // 0..1791 local chunk
        uint32_t lr  = l / 224u;                // 0..7 local row (magic-mul)
        uint32_t c4  = l - lr * 224u;           // chunk within row
        uint32_t row = row0 + lr;
        uint32_t col = c4 << 2;                 // f32 column 0..892

        f32x4 v;
        if (col < 128u) {
            // char-embedding segment: gather 16B of table row
            int tok = seq[row];
            v = *(const f32x4*)(table + (size_t)tok * 128u + col);
        } else {
            // scattered pretrained segment: pret[b, c/4] (validity from offsets)
            uint32_t b = row >> 11;
            uint32_t c = row & 2047u;
            uint32_t p = c >> 2;
            int2 se = *(const int2*)(offsets + (((b << 9) + p) << 1));
            if ((int)c >= se.x && (int)c < se.y) {
                v = *(const f32x4*)(pret + (size_t)((b << 9) + p) * 768u + (col - 128u));
            } else {
                v = (f32x4){0.f, 0.f, 0.f, 0.f};
            }
        }
        out[chunk0 + l] = v;
    }
}

extern "C" void kernel_launch(void* const* d_in, const int* in_sizes, int n_in,
                              void* d_out, int out_size, void* d_ws, size_t ws_size,
                              hipStream_t stream) {
    const int*   seq     = (const int*)  d_in[0];
    const int*   offsets = (const int*)  d_in[1];
    const float* table   = (const float*)d_in[2];
    const float* pret    = (const float*)d_in[3];

    EmbeddingLayer_14516989460967_kernel<<<NBLOCKS, 256, 0, stream>>>(
        seq, offsets, table, pret, (f32x4*)d_out);
}

// Round 10
// 58.524 us; speedup vs baseline: 1.6743x; 1.3796x over previous
//
#include <hip/hip_runtime.h>
#include <stdint.h>

// B=32, C=2048, S=512, DC=128, P=768, ROW=896 f32 per (b,c) output row.
// One block = 16 complete output rows (= 4 subwords) = 56 KB contiguous.
//   Phase 1 (uniform): 512 char chunks, 2/thread — gather table[seq[row]].
//   Phase 2 (uniform): 768 unique pret chunks, 3/thread — load ONCE, store to
//     the 4 rows sharing the subword (in-register broadcast; rounds 8/9 proved
//     cache-based reuse fails — register reuse is the only one that sticks).
// Complete rows written per block => no cross-phase partial-row write streams
// (round 7's remaining flaw). No intra-wave char/scatter mixing (round 9's
// flaw). No nontemporal (round 6). No XCD swizzle (round 8).

typedef float f32x4 __attribute__((ext_vector_type(4)));

#define NBLOCKS 4096u   // 65536 rows / 16 rows per block

__global__ __launch_bounds__(256) void EmbeddingLayer_14516989460967_kernel(
    const int*   __restrict__ seq,      // [B*C] int32
    const int*   __restrict__ offsets,  // [B*S*2] int32 (start,end)
    const float* __restrict__ table,    // [VOCAB*128] f32
    const float* __restrict__ pret,     // [B*S*768] f32
    float*       __restrict__ out)      // [B*C*896] f32
{
    const uint32_t tid = threadIdx.x;
    const uint32_t r0  = blockIdx.x * 16u;   // first output row
    const uint32_t sp0 = blockIdx.x * 4u;    // first global subword (batch*512+p)

    // ---- Phase 1: char segment, out[row, 0:128] = table[seq[row]] ----
#pragma unroll
    for (uint32_t k = 0; k < 2u; ++k) {
        uint32_t ci  = k * 256u + tid;       // 0..511
        uint32_t row = r0 + (ci >> 5);       // 16 rows, 32 chunks each
        uint32_t col = (ci & 31u) << 2;
        int tok = seq[row];
        f32x4 v = *(const f32x4*)(table + (size_t)tok * 128u + col);
        *(f32x4*)(out + (size_t)row * 896u + col) = v;
    }

    // ---- Phase 2: scatter segment, out[row(sp,j), 128:896] = pret[sp] ----
#pragma unroll
    for (uint32_t k = 0; k < 3u; ++k) {
        uint32_t u  = k * 256u + tid;        // 0..767 unique pret chunk
        uint32_t ls = u / 192u;              // 0..3 local subword (wave-uniform)
        uint32_t ck = u - ls * 192u;         // chunk within 768-wide pret row
        uint32_t sp = sp0 + ls;
        int2 se = *(const int2*)(offsets + (sp << 1));    // broadcast load
        f32x4 v = *(const f32x4*)(pret + (size_t)sp * 768u + (ck << 2));
        uint32_t c0 = (sp & 511u) << 2;      // char position of j=0 within batch
        float* dst = out + (size_t)(r0 + (ls << 2)) * 896u + 128u + (ck << 2);
        const f32x4 z = {0.f, 0.f, 0.f, 0.f};
#pragma unroll
        for (uint32_t j = 0; j < 4u; ++j) {
            int c = (int)(c0 + j);
            f32x4 w = (c >= se.x && c < se.y) ? v : z;
            *(f32x4*)(dst + (size_t)j * 896u) = w;
        }
    }
}

extern "C" void kernel_launch(void* const* d_in, const int* in_sizes, int n_in,
                              void* d_out, int out_size, void* d_ws, size_t ws_size,
                              hipStream_t stream) {
    const int*   seq     = (const int*)  d_in[0];
    const int*   offsets = (const int*)  d_in[1];
    const float* table   = (const float*)d_in[2];
    const float* pret    = (const float*)d_in[3];

    EmbeddingLayer_14516989460967_kernel<<<NBLOCKS, 256, 0, stream>>>(
        seq, offsets, table, pret, (float*)d_out);
}

// Round 11
// 54.442 us; speedup vs baseline: 1.7999x; 1.0750x over previous
//
#include <hip/hip_runtime.h>
#include <stdint.h>

// B=32, C=2048, S=512, DC=128, P=768, ROW=896 f32 per (b,c) output row.
// BEST STRUCTURE (round 7, 54.3 us = 5.56 TB/s effective on 302 MB ideal):
// Phase A (scatter, blocks [0,12288)): each thread loads one pret float4 ONCE
//   and broadcasts it to the 4 output rows sharing subword p (in-register
//   reuse — the only reuse formulation that held: L1 (r9) and cross-XCD L2
//   (r8) both failed; complete-rows-per-block (r10) also regressed).
// Phase B (char, blocks [12288,20480)): gather table rows, 1 float4/thread.
// No nontemporal hints (r6: -0.9 TB/s). No XCD swizzle (r8: +44 us).

#define SCAT_THREADS (32u * 512u * 192u)   // B*S*(768/4) = 3,145,728 (= 12288 blocks)
#define CHAR_CHUNKS  (32u * 2048u * 32u)   // B*C*(128/4) = 2,097,152 (=  8192 blocks)

typedef float f32x4 __attribute__((ext_vector_type(4)));

__global__ __launch_bounds__(256) void EmbeddingLayer_14516989460967_kernel(
    const int*   __restrict__ seq,      // [B*C] int32
    const int*   __restrict__ offsets,  // [B*S*2] int32 (start,end)
    const float* __restrict__ table,    // [VOCAB*128] f32
    const float* __restrict__ pret,     // [B*S*768] f32
    float*       __restrict__ out)      // [B*C*896] f32
{
    uint32_t gtid = blockIdx.x * 256u + threadIdx.x;

    if (gtid < SCAT_THREADS) {
        // ---- scattered segment: out[b, 4p+j, 128:896] = pret[b,p] ----
        uint32_t sp  = gtid / 192u;          // (b<<9)|p
        uint32_t ck  = gtid - sp * 192u;     // float4 chunk within 768-wide row
        int2 se = *(const int2*)(offsets + (sp << 1));   // wave-uniform broadcast
        f32x4 v = *(const f32x4*)(pret + (size_t)sp * 768u + (ck << 2));
        uint32_t b  = sp >> 9;
        uint32_t c0 = (sp & 511u) << 2;      // first char of span candidate
        float* dst = out + ((size_t)((b << 11) + c0)) * 896u + 128u + (ck << 2);
        const f32x4 z = {0.f, 0.f, 0.f, 0.f};
#pragma unroll
        for (int j = 0; j < 4; ++j) {
            int c = (int)c0 + j;
            f32x4 w = (c >= se.x && c < se.y) ? v : z;
            *(f32x4*)(dst + (size_t)j * 896u) = w;
        }
    } else {
        // ---- char-embedding segment: out[b,c,0:128] = table[seq[b,c]] ----
        uint32_t cid = gtid - SCAT_THREADS;
        uint32_t row = cid >> 5;             // (b,c) flat row
        uint32_t col = (cid & 31u) << 2;     // 0..124
        int tok = seq[row];
        f32x4 v = *(const f32x4*)(table + (size_t)tok * 128u + col);
        *(f32x4*)(out + (size_t)row * 896u + col) = v;
    }
}

extern "C" void kernel_launch(void* const* d_in, const int* in_sizes, int n_in,
                              void* d_out, int out_size, void* d_ws, size_t ws_size,
                              hipStream_t stream) {
    const int*   seq     = (const int*)  d_in[0];
    const int*   offsets = (const int*)  d_in[1];
    const float* table   = (const float*)d_in[2];
    const float* pret    = (const float*)d_in[3];

    uint32_t total_threads = SCAT_THREADS + CHAR_CHUNKS;   // 5,242,880
    uint32_t blocks = total_threads / 256u;                // 20,480 exact
    EmbeddingLayer_14516989460967_kernel<<<blocks, 256, 0, stream>>>(
        seq, offsets, table, pret, (float*)d_out);
}